// Round 12
// baseline (402.154 us; speedup 1.0000x reference)
//
#include <hip/hip_runtime.h>
#include <hip/hip_bf16.h>
#include <cstdint>
#include <cstddef>

// Problem constants
#define NN 20000
#define EE 320000
#define ET (EE + NN)     // edges + self loops
#define MPAD 20096       // 157 * 128, M padded to tile
#define SCHUNK 20        // scan_fast: counts per thread (1024*20 >= NN)

typedef __attribute__((ext_vector_type(8))) short  short8;   // 8 bf16 (4 VGPRs)
typedef __attribute__((ext_vector_type(4))) float  floatx4;  // MFMA C/D frag

__device__ inline unsigned short f2bf(float f) {   // RNE fp32 -> bf16
    unsigned u = __float_as_uint(f);
    u += 0x7FFFu + ((u >> 16) & 1u);
    return (unsigned short)(u >> 16);
}
__device__ inline float bf2f(unsigned short b) {
    return __uint_as_float(((unsigned)b) << 16);
}
// packed bf16x2 in a uint -> two floats
__device__ inline float bflo(unsigned u) { return __uint_as_float(u << 16); }
__device__ inline float bfhi(unsigned u) { return __uint_as_float(u & 0xFFFF0000u); }

// ---------------------------------------------------------------------------
// Utility kernels
// ---------------------------------------------------------------------------
__global__ void zero_i32(int* __restrict__ p, int n) {
    int i = blockIdx.x * blockDim.x + threadIdx.x;
    if (i < n) p[i] = 0;
}

// All three W [K,N] fp32 -> Wt [N,K] bf16 in ONE dispatch (flat-index split).
#define W1SZ (512 * 512)
#define W2SZ (512 * 256)
#define W3SZ (256 * 128)
#define NW_BLOCKS ((W1SZ + W2SZ + W3SZ) / 256)         // 1664
__global__ void cvt_w_all(const float* __restrict__ W1, unsigned short* __restrict__ Wt1,
                          const float* __restrict__ W2, unsigned short* __restrict__ Wt2,
                          const float* __restrict__ W3, unsigned short* __restrict__ Wt3) {
    int i = blockIdx.x * blockDim.x + threadIdx.x;
    const float* W; unsigned short* Wt; int K, N, idx;
    if (i < W1SZ)                    { W = W1; Wt = Wt1; K = 512; N = 512; idx = i; }
    else if (i < W1SZ + W2SZ)        { W = W2; Wt = Wt2; K = 512; N = 256; idx = i - W1SZ; }
    else if (i < W1SZ + W2SZ + W3SZ) { W = W3; Wt = Wt3; K = 256; N = 128; idx = i - W1SZ - W2SZ; }
    else return;
    int k = idx / N, n = idx - k * N;
    Wt[(size_t)n * K + k] = f2bf(W[idx]);
}

// ---------------------------------------------------------------------------
// CSR build: count -> scan_fast -> fill
// ---------------------------------------------------------------------------
__global__ void count_edges(const int* __restrict__ dst, int* __restrict__ cnt) {
    int e = blockIdx.x * blockDim.x + threadIdx.x;
    if (e >= ET) return;
    int d = (e < EE) ? dst[e] : (e - EE);
    atomicAdd(&cnt[d], 1);
}

__global__ __launch_bounds__(1024) void scan_fast(const int* __restrict__ cnt,
                                                  int* __restrict__ rowp,
                                                  int* __restrict__ wptr, int n) {
    __shared__ int sums[1024];
    const int t = threadIdx.x;
    const int base = t * SCHUNK;
    int local[SCHUNK];
    int acc = 0;
#pragma unroll
    for (int i = 0; i < SCHUNK; ++i) {
        int idx = base + i;
        int v = (idx < n) ? cnt[idx] : 0;
        local[i] = acc;          // exclusive within thread
        acc += v;
    }
    sums[t] = acc;
    __syncthreads();
    for (int o = 1; o < 1024; o <<= 1) {
        int u = (t >= o) ? sums[t - o] : 0;
        __syncthreads();
        sums[t] += u;
        __syncthreads();
    }
    int excl = sums[t] - acc;    // exclusive prefix of this thread's range
#pragma unroll
    for (int i = 0; i < SCHUNK; ++i) {
        int idx = base + i;
        if (idx < n) { int rp = excl + local[i]; rowp[idx] = rp; wptr[idx] = rp; }
    }
    if (t == 1023) rowp[n] = sums[1023];
}

__global__ void fill_edges(const int* __restrict__ src, const int* __restrict__ dst,
                           int* __restrict__ wptr, int* __restrict__ colx) {
    int e = blockIdx.x * blockDim.x + threadIdx.x;
    if (e >= ET) return;
    int s, d;
    if (e < EE) { s = src[e]; d = dst[e]; } else { s = e - EE; d = e - EE; }
    int pos = atomicAdd(&wptr[d], 1);
    colx[pos] = s;
}

// ---------------------------------------------------------------------------
// BF16 MFMA GEMM with fused epilogue (node-major outputs).
// MODE 1 (CAST): A is fp32 (raw x), f2bf during staging. MODE 2 (BN): A is
// fp32 agg output; per-channel scale/shift + ELU + f2bf during staging.
// R12: LDS tile stride 40 -> 42 ushorts (21 words). With stride 20 words,
// mrow*20 mod 32 has period 8 -> systematic multi-way bank conflicts on every
// ds_read_b128 (measured 2.57M/dispatch, present since R0). Stride 21:
// mrow*21 mod 32 distinct for all 16 mrows; each row's 16-bank span tiles the
// 32 banks evenly -> conflict-free reads AND writes (same index family).
// XCD-grouped swizzle kept (R11): all gx col-blocks of one 128-row A panel on
// one XCD (by % 8 == XCD), panel L2-resident. gy padded to 160; OOB-y blocks
// return uniformly before any sync.
// C[M,N] = A[Mpad,K] * Bt[N,K]^T. 128x128 tile, 4 waves, 16x16x32 MFMA.
// ---------------------------------------------------------------------------
template <int MODE>
__global__ __launch_bounds__(256) void gemm_bf16_fused(
        const float* __restrict__ A, const unsigned short* __restrict__ Bt,
        unsigned short* __restrict__ hN, float* __restrict__ aS, float* __restrict__ aD,
        const float* __restrict__ atts, const float* __restrict__ attd,
        const float* __restrict__ ssg,
        int M, int N, int K, int Mreal, int gxsh, int gy) {
    __shared__ unsigned short As[128][42];
    __shared__ unsigned short Bs[128][42];
    __shared__ float ssS[512];
    __shared__ float ssH[512];

    // XCD-grouped block swizzle (bijective: grid = gx * 160, multiple of 8)
    const int lid = blockIdx.x;
    const int c8 = lid & 7, kk = lid >> 3;
    const int bx = kk & ((1 << gxsh) - 1);
    const int by = c8 + 8 * (kk >> gxsh);
    if (by >= gy) return;                      // uniform per block, pre-sync

    const int t = threadIdx.x;
    const int lane = t & 63, wave = t >> 6;
    const int wm = wave >> 1, wn = wave & 1;
    const int quad = lane >> 4, mrow = lane & 15;
    const int row0 = by * 128, col0 = bx * 128;
    const int srow = t >> 2, schunk = (t & 3) * 8;

    if constexpr (MODE == 2) {
        for (int i = t; i < K; i += 256) { ssS[i] = ssg[i]; ssH[i] = ssg[K + i]; }
        __syncthreads();
    }

    floatx4 acc[4][4];
#pragma unroll
    for (int i = 0; i < 4; ++i)
#pragma unroll
        for (int j = 0; j < 4; ++j)
#pragma unroll
            for (int r = 0; r < 4; ++r) acc[i][j][r] = 0.f;

    for (int k0 = 0; k0 < K; k0 += 32) {
        float sc[8], sh[8];
        if constexpr (MODE == 2) {
#pragma unroll
            for (int i = 0; i < 8; ++i) { sc[i] = ssS[k0 + schunk + i]; sh[i] = ssH[k0 + schunk + i]; }
        }
        auto stage_row = [&](int arow) -> uint4 {
            uint4 r = make_uint4(0u, 0u, 0u, 0u);
            if (arow < Mreal) {
                float4 f0 = *(const float4*)(A + (size_t)arow * K + k0 + schunk);
                float4 f1 = *(const float4*)(A + (size_t)arow * K + k0 + schunk + 4);
                float v[8] = { f0.x, f0.y, f0.z, f0.w, f1.x, f1.y, f1.z, f1.w };
                unsigned short h[8];
#pragma unroll
                for (int i = 0; i < 8; ++i) {
                    float u = v[i];
                    if constexpr (MODE == 2) {
                        u = u * sc[i] + sh[i];
                        u = (u > 0.f) ? u : (__expf(u) - 1.f);
                    }
                    h[i] = f2bf(u);
                }
                r = make_uint4((unsigned)h[0] | ((unsigned)h[1] << 16),
                               (unsigned)h[2] | ((unsigned)h[3] << 16),
                               (unsigned)h[4] | ((unsigned)h[5] << 16),
                               (unsigned)h[6] | ((unsigned)h[7] << 16));
            }
            return r;
        };
        uint4 ra0 = stage_row(row0 + srow);
        uint4 ra1 = stage_row(row0 + srow + 64);
        uint4 rb0 = *(const uint4*)(Bt + (size_t)(col0 + srow)      * K + k0 + schunk);
        uint4 rb1 = *(const uint4*)(Bt + (size_t)(col0 + srow + 64) * K + k0 + schunk);
        __syncthreads();
        *(uint4*)&As[srow][schunk]      = ra0;
        *(uint4*)&As[srow + 64][schunk] = ra1;
        *(uint4*)&Bs[srow][schunk]      = rb0;
        *(uint4*)&Bs[srow + 64][schunk] = rb1;
        __syncthreads();

        short8 af[4], bfr[4];
#pragma unroll
        for (int i = 0; i < 4; ++i)
            af[i] = *(const short8*)&As[wm * 64 + i * 16 + mrow][quad * 8];
#pragma unroll
        for (int j = 0; j < 4; ++j)
            bfr[j] = *(const short8*)&Bs[wn * 64 + j * 16 + mrow][quad * 8];
#pragma unroll
        for (int i = 0; i < 4; ++i)
#pragma unroll
            for (int j = 0; j < 4; ++j)
                acc[i][j] = __builtin_amdgcn_mfma_f32_16x16x32_bf16(af[i], bfr[j], acc[i][j], 0, 0, 0);
    }

    // ---- fused epilogue ----
    const int head = (col0 + wn * 64) >> 6;
    float attS[4], attD[4];
#pragma unroll
    for (int j = 0; j < 4; ++j) {
        attS[j] = atts[head * 64 + j * 16 + mrow];
        attD[j] = attd[head * 64 + j * 16 + mrow];
    }

#pragma unroll
    for (int i = 0; i < 4; ++i) {
#pragma unroll
        for (int r = 0; r < 4; ++r) {
            int row = row0 + wm * 64 + i * 16 + quad * 4 + r;
            float ps = acc[i][0][r] * attS[0] + acc[i][1][r] * attS[1]
                     + acc[i][2][r] * attS[2] + acc[i][3][r] * attS[3];
            float pd = acc[i][0][r] * attD[0] + acc[i][1][r] * attD[1]
                     + acc[i][2][r] * attD[2] + acc[i][3][r] * attD[3];
#pragma unroll
            for (int o = 1; o < 16; o <<= 1) {
                ps += __shfl_xor(ps, o);
                pd += __shfl_xor(pd, o);
            }
            if (row < M) {
                if (mrow == 0) {
                    aS[(size_t)head * M + row] = ps;   // head-major
                    aD[(size_t)head * M + row] = pd;
                }
#pragma unroll
                for (int j = 0; j < 4; ++j)
                    hN[(size_t)row * N + col0 + wn * 64 + j * 16 + mrow] = f2bf(acc[i][j][r]);
            }
        }
    }
}

// ---------------------------------------------------------------------------
// GAT aggregation + FUSED BN stage-1 partials (R9/R10-proven: 43us L1).
//  (1) LDS pair stores (BYTE OFFSET = sn*F*2, p) -- no per-lane 64-bit muls.
//  (2) uint4 gathers, 2 edges per 16-lane group: lane q&7 owns 8 channels
//      (16B), q>>3 picks edge parity -> 8 edges/iter, 4 independent loads.
//  (3) epilogue: shfl_xor(.,8) cross-reduce; BN quad cq = (q&7)*2 + (q>>3).
// 32-edge chunks, first chunk peeled, head->XCD pinning (blockIdx.x % 8).
// ---------------------------------------------------------------------------
template <int HH>
__global__ __launch_bounds__(256) void gat_agg_head32(
        const unsigned short* __restrict__ hN,
        const float* __restrict__ aS, const float* __restrict__ aD,
        const int* __restrict__ rowp, const int* __restrict__ colx,
        const float* __restrict__ bias, float* __restrict__ out,
        float* __restrict__ part, int Nn) {
    constexpr int F = HH * 64;
    constexpr unsigned F2 = F * 2;            // hN row stride in bytes
    constexpr int G = 8 / HH;                 // XCDs sharing one head
    __shared__ uint2 pair[4][4][33];          // [wave][grp][edge] (byteoff, p)
    __shared__ float red[4][16][9];           // [wave][q][8 vals + pad]
    const int L = blockIdx.x;
    const int x8 = L & 7;
    const int hd = x8 / G;                    // head pinned to XCD group
    const int nodeblk = (L >> 3) * G + (x8 & (G - 1));
    const int wave = threadIdx.x >> 6, lane = threadIdx.x & 63;
    const int grp = lane >> 4;                // 4 node-tasks per wave
    const int q   = lane & 15;
    const int eo  = q >> 3;                   // edge-parity slot (0/1)
    const int lo  = (q & 7) * 16;             // lane's 8-channel byte offset
    const int n = nodeblk * 16 + wave * 4 + grp;
    const bool valid = (n < Nn);

    const char* hb = (const char*)hN + hd * 128;   // head slice base (bytes)

    float a0 = 0.f, a1 = 0.f, a2 = 0.f, a3 = 0.f;
    float a4 = 0.f, a5 = 0.f, a6 = 0.f, a7 = 0.f;
    float4 o4 = make_float4(0.f, 0.f, 0.f, 0.f);

    if (valid) {
        const float* aSh = aS + (size_t)hd * Nn;
        const float adv = aD[(size_t)hd * Nn + n];
        const int b0 = rowp[n], b1 = rowp[n + 1];

        float m, s;

        auto gather = [&](int cnt) {
            for (int j = 0; j < cnt; j += 8) {
                uint2 x0 = pair[wave][grp][j + eo + 0];
                uint2 x1 = pair[wave][grp][j + eo + 2];
                uint2 x2 = pair[wave][grp][j + eo + 4];
                uint2 x3 = pair[wave][grp][j + eo + 6];
                uint4 v0 = *(const uint4*)(hb + x0.x + lo);
                uint4 v1 = *(const uint4*)(hb + x1.x + lo);
                uint4 v2 = *(const uint4*)(hb + x2.x + lo);
                uint4 v3 = *(const uint4*)(hb + x3.x + lo);
                float p0 = __uint_as_float(x0.y), p1 = __uint_as_float(x1.y);
                float p2 = __uint_as_float(x2.y), p3 = __uint_as_float(x3.y);
                a0 += p0 * bflo(v0.x) + p1 * bflo(v1.x) + p2 * bflo(v2.x) + p3 * bflo(v3.x);
                a1 += p0 * bfhi(v0.x) + p1 * bfhi(v1.x) + p2 * bfhi(v2.x) + p3 * bfhi(v3.x);
                a2 += p0 * bflo(v0.y) + p1 * bflo(v1.y) + p2 * bflo(v2.y) + p3 * bflo(v3.y);
                a3 += p0 * bfhi(v0.y) + p1 * bfhi(v1.y) + p2 * bfhi(v2.y) + p3 * bfhi(v3.y);
                a4 += p0 * bflo(v0.z) + p1 * bflo(v1.z) + p2 * bflo(v2.z) + p3 * bflo(v3.z);
                a5 += p0 * bfhi(v0.z) + p1 * bfhi(v1.z) + p2 * bfhi(v2.z) + p3 * bfhi(v3.z);
                a6 += p0 * bflo(v0.w) + p1 * bflo(v1.w) + p2 * bflo(v2.w) + p3 * bflo(v3.w);
                a7 += p0 * bfhi(v0.w) + p1 * bfhi(v1.w) + p2 * bfhi(v2.w) + p3 * bfhi(v3.w);
            }
        };

        // ---- chunk 0 (peeled: no rescale; every node has >=1 edge) ----
        {
            const int cnt = min(32, b1 - b0);
            int sn0 = 0, sn1 = 0;
            if (q < cnt)      sn0 = colx[b0 + q];
            if (q + 16 < cnt) sn1 = colx[b0 + q + 16];
            float t0 = aSh[sn0] + adv;               // row 0 safe for pad lanes
            float t1 = aSh[sn1] + adv;
            float e0 = (q < cnt)      ? ((t0 > 0.f) ? t0 : 0.2f * t0) : -1e30f;
            float e1 = (q + 16 < cnt) ? ((t1 > 0.f) ? t1 : 0.2f * t1) : -1e30f;
            float mc = fmaxf(e0, e1);
#pragma unroll
            for (int o = 8; o > 0; o >>= 1) mc = fmaxf(mc, __shfl_xor(mc, o));
            m = mc;
            float p0 = __expf(e0 - m);               // pad lanes: exp(-1e30-m) = 0
            float p1 = __expf(e1 - m);
            float ps = p0 + p1;
#pragma unroll
            for (int o = 8; o > 0; o >>= 1) ps += __shfl_xor(ps, o);
            s = ps;
            pair[wave][grp][q]      = make_uint2((unsigned)sn0 * F2, __float_as_uint(p0));
            pair[wave][grp][q + 16] = make_uint2((unsigned)sn1 * F2, __float_as_uint(p1));
            __threadfence_block();
            gather(cnt);
        }

        // ---- chunks 1.. (deg > 32 only; rare) ----
        for (int c0 = b0 + 32; c0 < b1; c0 += 32) {
            __threadfence_block();                   // prior gather done before overwrite
            const int cnt = min(32, b1 - c0);
            int sn0 = 0, sn1 = 0;
            if (q < cnt)      sn0 = colx[c0 + q];
            if (q + 16 < cnt) sn1 = colx[c0 + q + 16];
            float t0 = aSh[sn0] + adv;
            float t1 = aSh[sn1] + adv;
            float e0 = (q < cnt)      ? ((t0 > 0.f) ? t0 : 0.2f * t0) : -1e30f;
            float e1 = (q + 16 < cnt) ? ((t1 > 0.f) ? t1 : 0.2f * t1) : -1e30f;
            float mc = fmaxf(e0, e1);
#pragma unroll
            for (int o = 8; o > 0; o >>= 1) mc = fmaxf(mc, __shfl_xor(mc, o));
            float nm = fmaxf(m, mc);
            float sc = __expf(m - nm);
            float p0 = __expf(e0 - nm);
            float p1 = __expf(e1 - nm);
            float ps = p0 + p1;
#pragma unroll
            for (int o = 8; o > 0; o >>= 1) ps += __shfl_xor(ps, o);
            s = s * sc + ps;
            a0 *= sc; a1 *= sc; a2 *= sc; a3 *= sc;
            a4 *= sc; a5 *= sc; a6 *= sc; a7 *= sc;
            m = nm;
            pair[wave][grp][q]      = make_uint2((unsigned)sn0 * F2, __float_as_uint(p0));
            pair[wave][grp][q + 16] = make_uint2((unsigned)sn1 * F2, __float_as_uint(p1));
            __threadfence_block();
            gather(cnt);
        }

        // cross-reduce the even/odd edge partials (lanes q and q+8 share chans)
        a0 += __shfl_xor(a0, 8); a1 += __shfl_xor(a1, 8);
        a2 += __shfl_xor(a2, 8); a3 += __shfl_xor(a3, 8);
        a4 += __shfl_xor(a4, 8); a5 += __shfl_xor(a5, 8);
        a6 += __shfl_xor(a6, 8); a7 += __shfl_xor(a7, 8);

        const float inv = 1.f / s;
        float r0 = eo ? a4 : a0;
        float r1 = eo ? a5 : a1;
        float r2 = eo ? a6 : a2;
        float r3 = eo ? a7 : a3;
        const int cb = hd * 64 + (q & 7) * 8 + eo * 4;
        o4.x = r0 * inv + bias[cb + 0];
        o4.y = r1 * inv + bias[cb + 1];
        o4.z = r2 * inv + bias[cb + 2];
        o4.w = r3 * inv + bias[cb + 3];
        *(float4*)(out + (size_t)n * F + cb) = o4;
    }

    // ---- fused BN stage-1: per-block sum/sumsq of 64 channels over 16 nodes
    float s0 = o4.x, s1 = o4.y, s2 = o4.z, s3 = o4.w;
    float q0 = s0 * s0, q1 = s1 * s1, q2 = s2 * s2, q3 = s3 * s3;
#pragma unroll
    for (int o = 16; o < 64; o <<= 1) {        // sum over the 4 nodes in wave
        s0 += __shfl_xor(s0, o); s1 += __shfl_xor(s1, o);
        s2 += __shfl_xor(s2, o); s3 += __shfl_xor(s3, o);
        q0 += __shfl_xor(q0, o); q1 += __shfl_xor(q1, o);
        q2 += __shfl_xor(q2, o); q3 += __shfl_xor(q3, o);
    }
    if (grp == 0) {
        red[wave][q][0] = s0; red[wave][q][1] = s1;
        red[wave][q][2] = s2; red[wave][q][3] = s3;
        red[wave][q][4] = q0; red[wave][q][5] = q1;
        red[wave][q][6] = q2; red[wave][q][7] = q3;
    }
    __syncthreads();
    if (wave == 0 && lane < 16) {
        float a[8];
#pragma unroll
        for (int k = 0; k < 8; ++k)
            a[k] = red[0][q][k] + red[1][q][k] + red[2][q][k] + red[3][q][k];
        // lane q's 4 written channels start at (q&7)*8 + eo*4 -> quad index:
        const int cq = (q & 7) * 2 + eo;
        float* pb = part + (size_t)L * 128;
#pragma unroll
        for (int k = 0; k < 4; ++k) {
            pb[cq * 4 + k]      = a[k];
            pb[64 + cq * 4 + k] = a[4 + k];
        }
    }
}

// ---------------------------------------------------------------------------
// Layer-4 GEMM with FUSED BN+ELU A-staging (R8-proven): reads layer-3 agg
// output bufO fp32, applies bns (K=128) + ELU during As staging (fp32 in
// LDS -- no quantization). N=16. Writes bf16 hN and fused att dots (H=1).
// ---------------------------------------------------------------------------
__global__ __launch_bounds__(256) void gemm_l4_fused(const float* __restrict__ A,
                                                     const float* __restrict__ B,
                                                     unsigned short* __restrict__ C,
                                                     float* __restrict__ aS, float* __restrict__ aD,
                                                     const float* __restrict__ atts,
                                                     const float* __restrict__ attd,
                                                     const float* __restrict__ ssg,
                                                     int M, int N, int K, int Mreal) {
    __shared__ float As[16][65];
    __shared__ float Bs[16][64];
    const int tid = threadIdx.x;
    const int tx = tid & 15, ty = tid >> 4;
    const int row0 = blockIdx.y * 64, col0 = blockIdx.x * 64;
    const int rA = tid >> 2, kq = (tid & 3) << 2;
    const int rB = tid >> 4, cq = (tid & 15) << 2;
    float acc[4][4] = {};

    for (int k0 = 0; k0 < K; k0 += 16) {
        const int arow = row0 + rA;
        float a0v = 0.f, a1v = 0.f, a2v = 0.f, a3v = 0.f;
        if (arow < Mreal) {
            float4 fa = *(const float4*)(A + (size_t)arow * K + k0 + kq);
            const int c = k0 + kq;
            a0v = fa.x * ssg[c + 0] + ssg[K + c + 0];
            a1v = fa.y * ssg[c + 1] + ssg[K + c + 1];
            a2v = fa.z * ssg[c + 2] + ssg[K + c + 2];
            a3v = fa.w * ssg[c + 3] + ssg[K + c + 3];
            a0v = (a0v > 0.f) ? a0v : (__expf(a0v) - 1.f);
            a1v = (a1v > 0.f) ? a1v : (__expf(a1v) - 1.f);
            a2v = (a2v > 0.f) ? a2v : (__expf(a2v) - 1.f);
            a3v = (a3v > 0.f) ? a3v : (__expf(a3v) - 1.f);
        }
        float4 fb = make_float4(0.f, 0.f, 0.f, 0.f);
        int bcol = col0 + cq;
        if (bcol < N) fb = *(const float4*)(B + (size_t)(k0 + rB) * N + bcol);
        As[kq + 0][rA] = a0v; As[kq + 1][rA] = a1v;
        As[kq + 2][rA] = a2v; As[kq + 3][rA] = a3v;
        *(float4*)&Bs[rB][cq] = fb;
        __syncthreads();
#pragma unroll
        for (int k = 0; k < 16; ++k) {
            float a0 = As[k][ty * 4 + 0];
            float a1 = As[k][ty * 4 + 1];
            float a2 = As[k][ty * 4 + 2];
            float a3 = As[k][ty * 4 + 3];
            float4 b = *(float4*)&Bs[k][tx * 4];
            acc[0][0] += a0 * b.x; acc[0][1] += a0 * b.y; acc[0][2] += a0 * b.z; acc[0][3] += a0 * b.w;
            acc[1][0] += a1 * b.x; acc[1][1] += a1 * b.y; acc[1][2] += a1 * b.z; acc[1][3] += a1 * b.w;
            acc[2][0] += a2 * b.x; acc[2][1] += a2 * b.y; acc[2][2] += a2 * b.z; acc[2][3] += a2 * b.w;
            acc[3][0] += a3 * b.x; acc[3][1] += a3 * b.y; acc[3][2] += a3 * b.z; acc[3][3] += a3 * b.w;
        }
        __syncthreads();
    }
    float as_part[4], ad_part[4];
#pragma unroll
    for (int i = 0; i < 4; ++i) { as_part[i] = 0.f; ad_part[i] = 0.f; }
    if (tx < 4) {
#pragma unroll
        for (int i = 0; i < 4; ++i) {
#pragma unroll
            for (int jj = 0; jj < 4; ++jj) {
                int c = tx * 4 + jj;
                as_part[i] += acc[i][jj] * atts[c];
                ad_part[i] += acc[i][jj] * attd[c];
            }
        }
    }
#pragma unroll
    for (int i = 0; i < 4; ++i) {
        float ps = as_part[i], pd = ad_part[i];
        ps += __shfl_xor(ps, 1); ps += __shfl_xor(ps, 2);
        pd += __shfl_xor(pd, 1); pd += __shfl_xor(pd, 2);
        int r = row0 + ty * 4 + i;
        if (r < M) {
            if (tx == 0) { aS[r] = ps; aD[r] = pd; }
#pragma unroll
            for (int jj = 0; jj < 4; ++jj) {
                int c = col0 + tx * 4 + jj;
                if (c < N) C[(size_t)r * N + c] = f2bf(acc[i][jj]);
            }
        }
    }
}

// ---------------------------------------------------------------------------
// Layer-4 aggregation (H=1, C=16) with FUSED log_softmax. One wave per node.
// ---------------------------------------------------------------------------
template <int C>
__global__ void gat_agg_l4_ls(const unsigned short* __restrict__ ht,
                              const float* __restrict__ as, const float* __restrict__ aD,
                              const int* __restrict__ rowp, const int* __restrict__ colx,
                              const float* __restrict__ bias, float* __restrict__ out, int Nn) {
    int n = blockIdx.x * 4 + (threadIdx.x >> 6);
    int lane = threadIdx.x & 63;
    if (n >= Nn) return;
    float adv = aD[n];
    int b0 = rowp[n], b1 = rowp[n + 1];

    float m = -1e30f, s = 0.f, acc = 0.f;
    for (int c0 = b0; c0 < b1; c0 += 64) {
        int cnt = b1 - c0; if (cnt > 64) cnt = 64;
        int sn = 0; float e = -1e30f;
        if (lane < cnt) {
            sn = colx[c0 + lane];
            float tt = as[sn] + adv;
            e = (tt > 0.f) ? tt : 0.2f * tt;
        }
        float mc = e;
#pragma unroll
        for (int o = 32; o > 0; o >>= 1) mc = fmaxf(mc, __shfl_xor(mc, o));
        float nm = fmaxf(m, mc);
        float sc = __expf(m - nm);
        acc *= sc; s *= sc;
        float p = (lane < cnt) ? __expf(e - nm) : 0.f;
        float ps = p;
#pragma unroll
        for (int o = 32; o > 0; o >>= 1) ps += __shfl_xor(ps, o);
        s += ps; m = nm;

        int j = 0;
        for (; j + 4 <= cnt; j += 4) {
            int s0 = __shfl(sn, j),     s1 = __shfl(sn, j + 1);
            int s2 = __shfl(sn, j + 2), s3 = __shfl(sn, j + 3);
            float p0 = __shfl(p, j),     p1 = __shfl(p, j + 1);
            float p2 = __shfl(p, j + 2), p3 = __shfl(p, j + 3);
            float h0 = 0.f, h1 = 0.f, h2 = 0.f, h3 = 0.f;
            if (lane < C) {
                h0 = bf2f(ht[(size_t)s0 * C + lane]);
                h1 = bf2f(ht[(size_t)s1 * C + lane]);
                h2 = bf2f(ht[(size_t)s2 * C + lane]);
                h3 = bf2f(ht[(size_t)s3 * C + lane]);
            }
            acc += p0 * h0 + p1 * h1 + p2 * h2 + p3 * h3;
        }
        for (; j < cnt; ++j) {
            int sj = __shfl(sn, j);
            float pj = __shfl(p, j);
            float hv = (lane < C) ? bf2f(ht[(size_t)sj * C + lane]) : 0.f;
            acc += pj * hv;
        }
    }
    float v = (lane < C) ? (acc / s + bias[lane]) : -1e30f;
    float mx = v;
#pragma unroll
    for (int o = 8; o > 0; o >>= 1) mx = fmaxf(mx, __shfl_xor(mx, o));
    float ex = (lane < C) ? __expf(v - mx) : 0.f;
#pragma unroll
    for (int o = 8; o > 0; o >>= 1) ex += __shfl_xor(ex, o);
    float l = __logf(ex) + mx;
    if (lane < C) out[(size_t)n * C + lane] = v - l;
}

// ---------------------------------------------------------------------------
// BN final reduce over the agg kernel's per-block partials (R7-proven: 1024
// threads, 32 partial-rows, 4 independent accumulators -> short dep chain).
// Fixed iteration order -> deterministic.
// ---------------------------------------------------------------------------
template <int F>
__global__ __launch_bounds__(1024) void bn_reduce_par(const float* __restrict__ part,
                                                      const float* __restrict__ gamma,
                                                      const float* __restrict__ beta,
                                                      float* __restrict__ ss,
                                                      float invN, int NB8) {
    constexpr int G = 512 / F;      // XCD-groups per head (matches agg's G)
    __shared__ float sd[32][33];
    const int t = threadIdx.x;
    const int pr = t >> 5;          // partial-row 0..31
    const int tg = t & 31;          // 0-15: sum of col c0+tg; 16-31: sumsq
    const int c0 = blockIdx.x * 16;
    const int c  = c0 + (tg & 15);
    const int hd = c >> 6;
    const int off = (c & 63) + ((tg < 16) ? 0 : 64);
    float a0 = 0.f, a1 = 0.f, a2 = 0.f, a3 = 0.f;
    for (int g = 0; g < G; ++g) {
        const float* pb = part + (size_t)(hd * G + g) * 128 + off;
        int j = pr;
        for (; j + 96 < NB8; j += 128) {        // 4 independent loads in flight
            a0 += pb[(size_t)(j +  0) * 1024];
            a1 += pb[(size_t)(j + 32) * 1024];
            a2 += pb[(size_t)(j + 64) * 1024];
            a3 += pb[(size_t)(j + 96) * 1024];
        }
        for (; j < NB8; j += 32)
            a0 += pb[(size_t)j * 1024];
    }
    sd[pr][tg] = (a0 + a1) + (a2 + a3);
    __syncthreads();
    if (pr == 0) {
        float tot = sd[0][tg];
#pragma unroll
        for (int r = 1; r < 32; ++r) tot += sd[r][tg];   // fixed serial order
        sd[0][tg] = tot;
    }
    __syncthreads();
    if (t < 16) {
        int cc = c0 + t;
        float s = sd[0][t];
        float q = sd[0][16 + t];
        float mu = s * invN;
        float var = q * invN - mu * mu;
        float sc = gamma[cc] * rsqrtf(var + 1e-5f);
        ss[cc] = sc;
        ss[F + cc] = beta[cc] - mu * sc;
    }
}

// ---------------------------------------------------------------------------
// Launcher. 16 dispatches: CSR(4) + cvt_w_all + [gemm, agg, reduce] x3 +
// gemm_l4 + agg_l4. x->bf16 cast and BN-apply live inside GEMM A-staging.
// GEMM grids are 1D (gx*160) for the XCD-grouped swizzle.
// ---------------------------------------------------------------------------
extern "C" void kernel_launch(void* const* d_in, const int* in_sizes, int n_in,
                              void* d_out, int out_size, void* d_ws, size_t ws_size,
                              hipStream_t stream) {
    const float* x   = (const float*)d_in[0];
    const int*   ei  = (const int*)d_in[1];
    const float* W1  = (const float*)d_in[2];
    const float* as1 = (const float*)d_in[3];
    const float* ad1 = (const float*)d_in[4];
    const float* b1  = (const float*)d_in[5];
    const float* ga1 = (const float*)d_in[6];
    const float* be1 = (const float*)d_in[7];
    const float* W2  = (const float*)d_in[8];
    const float* as2 = (const float*)d_in[9];
    const float* ad2 = (const float*)d_in[10];
    const float* b2  = (const float*)d_in[11];
    const float* ga2 = (const float*)d_in[12];
    const float* be2 = (const float*)d_in[13];
    const float* W3  = (const float*)d_in[14];
    const float* as3 = (const float*)d_in[15];
    const float* ad3 = (const float*)d_in[16];
    const float* b3  = (const float*)d_in[17];
    const float* ga3 = (const float*)d_in[18];
    const float* be3 = (const float*)d_in[19];
    const float* W4  = (const float*)d_in[20];
    const float* as4 = (const float*)d_in[21];
    const float* ad4 = (const float*)d_in[22];
    const float* b4  = (const float*)d_in[23];
    float* outp = (float*)d_out;

    uint8_t* base = (uint8_t*)d_ws;
    size_t off = 0;
    auto alloc = [&](size_t nbytes) -> void* {
        off = (off + 255) & ~(size_t)255;
        void* p = base + off;
        off += nbytes;
        return p;
    };
    float* bufO = (float*)alloc((size_t)NN * 512 * 4);                       // agg out (fp32)
    unsigned short* hN   = (unsigned short*)alloc((size_t)NN * 512 * 2);     // bf16 node-major h
    unsigned short* Wt1  = (unsigned short*)alloc((size_t)512 * 512 * 2);
    unsigned short* Wt2  = (unsigned short*)alloc((size_t)256 * 512 * 2);
    unsigned short* Wt3  = (unsigned short*)alloc((size_t)128 * 256 * 2);
    float* aSn  = (float*)alloc((size_t)NN * 8 * 4);
    float* aDn  = (float*)alloc((size_t)NN * 8 * 4);
    int*   cnt  = (int*)alloc((size_t)NN * 4);
    int*   rowp = (int*)alloc((size_t)(NN + 1) * 4);
    int*   wptr = (int*)alloc((size_t)NN * 4);
    int*   colx = (int*)alloc((size_t)ET * 4);
    float* bnp  = (float*)alloc((size_t)10048 * 128 * 4);    // agg-block BN partials
    float* bns  = (float*)alloc((size_t)1024 * 4);           // scale/shift

    const int* srcRow = ei;
    const int* dstRow = ei + EE;

    // ---- CSR build ----
    zero_i32<<<(NN + 255) / 256, 256, 0, stream>>>(cnt, NN);
    count_edges<<<(ET + 255) / 256, 256, 0, stream>>>(dstRow, cnt);
    scan_fast<<<1, 1024, 0, stream>>>(cnt, rowp, wptr, NN);
    fill_edges<<<(ET + 255) / 256, 256, 0, stream>>>(srcRow, dstRow, wptr, colx);

    // ---- weight transposes (x-cast fused into L1 GEMM) ----
    cvt_w_all<<<NW_BLOCKS, 256, 0, stream>>>(W1, Wt1, W2, Wt2, W3, Wt3);

    const int NBLK = (NN + 15) / 16;   // 16-node task blocks (=1250)
    const int GY8 = 160;               // 157 row-panels padded to mult of 8

    // ---- Layer 1: Fin=512, H=8, C=64 (F=512); x cast fused in staging ----
    {
        gemm_bf16_fused<1><<<4 * GY8, 256, 0, stream>>>(x, Wt1, hN, aSn, aDn, as1, ad1,
                                                        nullptr, NN, 512, 512, NN, 2, 157);
        gat_agg_head32<8><<<NBLK * 8, 256, 0, stream>>>(hN, aSn, aDn, rowp, colx, b1, bufO, bnp, NN);
        bn_reduce_par<512><<<512 / 16, 1024, 0, stream>>>(bnp, ga1, be1, bns, 1.0f / NN, NBLK);
    }
    // ---- Layer 2: Fin=512, H=4, C=64 (F=256); BN+ELU fused into A-staging ----
    {
        gemm_bf16_fused<2><<<2 * GY8, 256, 0, stream>>>(bufO, Wt2, hN, aSn, aDn, as2, ad2,
                                                        bns, NN, 256, 512, NN, 1, 157);
        const int nb8 = (NBLK + 1) / 2;
        gat_agg_head32<4><<<nb8 * 8, 256, 0, stream>>>(hN, aSn, aDn, rowp, colx, b2, bufO, bnp, NN);
        bn_reduce_par<256><<<256 / 16, 1024, 0, stream>>>(bnp, ga2, be2, bns, 1.0f / NN, nb8);
    }
    // ---- Layer 3: Fin=256, H=2, C=64 (F=128); BN+ELU fused into A-staging ----
    {
        gemm_bf16_fused<2><<<1 * GY8, 256, 0, stream>>>(bufO, Wt3, hN, aSn, aDn, as3, ad3,
                                                        bns, NN, 128, 256, NN, 0, 157);
        const int nb8 = (NBLK + 3) / 4;
        gat_agg_head32<2><<<nb8 * 8, 256, 0, stream>>>(hN, aSn, aDn, rowp, colx, b3, bufO, bnp, NN);
        bn_reduce_par<128><<<128 / 16, 1024, 0, stream>>>(bnp, ga3, be3, bns, 1.0f / NN, nb8);
    }
    // ---- Layer 4: Fin=128, H=1, C=16; BN+ELU fused into A-staging (fp32) ----
    {
        dim3 g(1, (NN + 63) / 64);
        gemm_l4_fused<<<g, 256, 0, stream>>>(bufO, W4, hN, aSn, aDn, as4, ad4,
                                             bns, NN, 16, 128, NN);
        gat_agg_l4_ls<16><<<(NN + 3) / 4, 256, 0, stream>>>(hN, aSn, aDn, rowp, colx, b4, outp, NN);
    }
}

// Round 14
// 390.261 us; speedup vs baseline: 1.0305x; 1.0305x over previous
//
#include <hip/hip_runtime.h>
#include <hip/hip_bf16.h>
#include <cstdint>
#include <cstddef>

// Problem constants
#define NN 20000
#define EE 320000
#define ET (EE + NN)     // edges + self loops
#define MPAD 20096       // 157 * 128, M padded to tile
#define SCHUNK 20        // scan_fast: counts per thread (1024*20 >= NN)

typedef __attribute__((ext_vector_type(8))) short  short8;   // 8 bf16 (4 VGPRs)
typedef __attribute__((ext_vector_type(4))) float  floatx4;  // MFMA C/D frag

__device__ inline unsigned short f2bf(float f) {   // RNE fp32 -> bf16
    unsigned u = __float_as_uint(f);
    u += 0x7FFFu + ((u >> 16) & 1u);
    return (unsigned short)(u >> 16);
}
__device__ inline float bf2f(unsigned short b) {
    return __uint_as_float(((unsigned)b) << 16);
}
// packed bf16x2 in a uint -> two floats
__device__ inline float bflo(unsigned u) { return __uint_as_float(u << 16); }
__device__ inline float bfhi(unsigned u) { return __uint_as_float(u & 0xFFFF0000u); }

// Tile-fragment chunk decode: ch in [0,512) -> (row_local, k_local) of a
// 128x32 tile. chunk = wm*256 + i*64 + quad*16 + mrow  (16B = 8 bf16 each).
// The GEMM reads frag (wave wm/wn, rep i, lane) at chunk wm*256+i*64+lane,
// i.e. LDS byte lane*16 within the frag group -> canonical even-bank access.
__device__ inline void chunk_decode(int ch, int& rl, int& kl) {
    const int wm = ch >> 8, i = (ch >> 6) & 3, quad = (ch >> 4) & 3, mrow = ch & 15;
    rl = wm * 64 + i * 16 + mrow;
    kl = quad * 8;
}
__device__ inline uint4 pack8(const float* v) {
    unsigned short h[8];
#pragma unroll
    for (int e = 0; e < 8; ++e) h[e] = f2bf(v[e]);
    return make_uint4((unsigned)h[0] | ((unsigned)h[1] << 16),
                      (unsigned)h[2] | ((unsigned)h[3] << 16),
                      (unsigned)h[4] | ((unsigned)h[5] << 16),
                      (unsigned)h[6] | ((unsigned)h[7] << 16));
}

// ---------------------------------------------------------------------------
// Utility kernels
// ---------------------------------------------------------------------------
__global__ void zero_i32(int* __restrict__ p, int n) {
    int i = blockIdx.x * blockDim.x + threadIdx.x;
    if (i < n) p[i] = 0;
}

// ONE dispatch: x fp32 -> PERMUTED bf16 A tiles [157][16][512chunks], plus all
// three W -> PERMUTED bf16 B tiles [NT][KS][512chunks].
#define NA_CHUNKS (157 * 16 * 512)             // 1286144
#define NA_BLOCKS (NA_CHUNKS / 256)            // 5024
#define W1C (4 * 16 * 512)                     // 32768
#define W2C (2 * 16 * 512)                     // 16384
#define W3C (1 * 8 * 512)                      // 4096
#define NW_BLOCKS ((W1C + W2C + W3C) / 256)    // 208
__global__ void prep_all(const float* __restrict__ x, unsigned short* __restrict__ Ap,
                         const float* __restrict__ W1, unsigned short* __restrict__ Wt1,
                         const float* __restrict__ W2, unsigned short* __restrict__ Wt2,
                         const float* __restrict__ W3, unsigned short* __restrict__ Wt3) {
    const int b = blockIdx.x;
    if (b < NA_BLOCKS) {
        const int c = b * 256 + threadIdx.x;
        const int rt = c >> 13;                // /(16*512)
        const int rem = c & 8191;
        const int ks = rem >> 9, ch = rem & 511;
        int rl, kl; chunk_decode(ch, rl, kl);
        const int row = rt * 128 + rl;
        const int k = ks * 32 + kl;
        uint4 o = make_uint4(0u, 0u, 0u, 0u);
        if (row < NN) {
            float4 f0 = *(const float4*)(x + (size_t)row * 512 + k);
            float4 f1 = *(const float4*)(x + (size_t)row * 512 + k + 4);
            float v[8] = { f0.x, f0.y, f0.z, f0.w, f1.x, f1.y, f1.z, f1.w };
            o = pack8(v);
        }
        *(uint4*)(Ap + (size_t)c * 8) = o;
    } else {
        int i2 = (b - NA_BLOCKS) * 256 + threadIdx.x;
        const float* W; unsigned short* Wt; int Nw, KSw, c;
        if (i2 < W1C)              { W = W1; Wt = Wt1; Nw = 512; KSw = 16; c = i2; }
        else if (i2 < W1C + W2C)   { W = W2; Wt = Wt2; Nw = 256; KSw = 16; c = i2 - W1C; }
        else                       { W = W3; Wt = Wt3; Nw = 128; KSw = 8;  c = i2 - W1C - W2C; }
        const int cpt = KSw * 512;
        const int nt = c / cpt;
        const int rem = c - nt * cpt;
        const int ks = rem >> 9, ch = rem & 511;
        int rl, kl; chunk_decode(ch, rl, kl);
        const int n = nt * 128 + rl;
        const int k = ks * 32 + kl;
        float v[8];
#pragma unroll
        for (int e = 0; e < 8; ++e) v[e] = W[(size_t)(k + e) * Nw + n];
        *(uint4*)(Wt + (size_t)c * 8) = pack8(v);
    }
}

// BN+ELU+cast applied to agg output bufO (fp32 [NN][F]) -> PERMUTED bf16 A
// tiles [157][F/32][512chunks] for the next layer's GEMM. Same math as the
// R5-R7 proven bn_apply_elu_bf16 (bit-identical f2bf); pad rows -> zeros.
template <int F>
__global__ void bn_apply_perm(const float* __restrict__ xin, const float* __restrict__ ss,
                              unsigned short* __restrict__ Ap, int Nn) {
    constexpr int CPT = (F / 32) * 512;        // chunks per 128-row tile
    constexpr int SH = (F == 512) ? 13 : 12;   // log2(CPT)
    const int c = blockIdx.x * 256 + threadIdx.x;
    const int rt = c >> SH;
    const int rem = c & (CPT - 1);
    const int ks = rem >> 9, ch = rem & 511;
    int rl, kl; chunk_decode(ch, rl, kl);
    const int row = rt * 128 + rl;
    const int k = ks * 32 + kl;
    uint4 o = make_uint4(0u, 0u, 0u, 0u);
    if (row < Nn) {
        float4 f0 = *(const float4*)(xin + (size_t)row * F + k);
        float4 f1 = *(const float4*)(xin + (size_t)row * F + k + 4);
        float v[8] = { f0.x, f0.y, f0.z, f0.w, f1.x, f1.y, f1.z, f1.w };
#pragma unroll
        for (int e = 0; e < 8; ++e) {
            float u = v[e] * ss[k + e] + ss[F + k + e];
            v[e] = (u > 0.f) ? u : (__expf(u) - 1.f);
        }
        o = pack8(v);
    }
    *(uint4*)(Ap + (size_t)c * 8) = o;
}

// ---------------------------------------------------------------------------
// CSR build: count -> scan_fast -> fill
// ---------------------------------------------------------------------------
__global__ void count_edges(const int* __restrict__ dst, int* __restrict__ cnt) {
    int e = blockIdx.x * blockDim.x + threadIdx.x;
    if (e >= ET) return;
    int d = (e < EE) ? dst[e] : (e - EE);
    atomicAdd(&cnt[d], 1);
}

__global__ __launch_bounds__(1024) void scan_fast(const int* __restrict__ cnt,
                                                  int* __restrict__ rowp,
                                                  int* __restrict__ wptr, int n) {
    __shared__ int sums[1024];
    const int t = threadIdx.x;
    const int base = t * SCHUNK;
    int local[SCHUNK];
    int acc = 0;
#pragma unroll
    for (int i = 0; i < SCHUNK; ++i) {
        int idx = base + i;
        int v = (idx < n) ? cnt[idx] : 0;
        local[i] = acc;          // exclusive within thread
        acc += v;
    }
    sums[t] = acc;
    __syncthreads();
    for (int o = 1; o < 1024; o <<= 1) {
        int u = (t >= o) ? sums[t - o] : 0;
        __syncthreads();
        sums[t] += u;
        __syncthreads();
    }
    int excl = sums[t] - acc;    // exclusive prefix of this thread's range
#pragma unroll
    for (int i = 0; i < SCHUNK; ++i) {
        int idx = base + i;
        if (idx < n) { int rp = excl + local[i]; rowp[idx] = rp; wptr[idx] = rp; }
    }
    if (t == 1023) rowp[n] = sums[1023];
}

__global__ void fill_edges(const int* __restrict__ src, const int* __restrict__ dst,
                           int* __restrict__ wptr, int* __restrict__ colx) {
    int e = blockIdx.x * blockDim.x + threadIdx.x;
    if (e >= ET) return;
    int s, d;
    if (e < EE) { s = src[e]; d = dst[e]; } else { s = e - EE; d = e - EE; }
    int pos = atomicAdd(&wptr[d], 1);
    colx[pos] = s;
}

// ---------------------------------------------------------------------------
// BF16 MFMA GEMM, PERMUTED operands (R13/R14). A and B arrive in
// tile-fragment order: [tile][kstep][512 chunks of 16B]. Staging = 2 chunks
// per thread per operand (t and t+256): contiguous 4KB runs, coalesced ->
// LDS linear (even banks by construction). Fragment reads at chunk
// (wm*256+i*64+lane) = lane*16B within the frag group -> even banks.
// Unpadded 2x8KB LDS. No transform in the loop. XCD-grouped swizzle (R11):
// by % 8 == XCD, A panel L2-resident across its col-blocks.
// R14 fix: R13 staged only HALF the tile (1 chunk/thread) -> garbage frags.
// C[M,N] = A[Mpad,K] * Bt[N,K]^T. 128x128 tile, 4 waves, 16x16x32 MFMA.
// ---------------------------------------------------------------------------
__global__ __launch_bounds__(256) void gemm_bf16_fused(
        const unsigned short* __restrict__ Ap, const unsigned short* __restrict__ Btp,
        unsigned short* __restrict__ hN, float* __restrict__ aS, float* __restrict__ aD,
        const float* __restrict__ atts, const float* __restrict__ attd,
        int M, int N, int K, int gxsh, int gy) {
    __shared__ unsigned short As[4096];        // 512 chunks * 16B = 8KB
    __shared__ unsigned short Bs[4096];

    // XCD-grouped block swizzle (grid = gx * 160, multiple of 8)
    const int lid = blockIdx.x;
    const int c8 = lid & 7, kkk = lid >> 3;
    const int bx = kkk & ((1 << gxsh) - 1);
    const int by = c8 + 8 * (kkk >> gxsh);
    if (by >= gy) return;                      // uniform per block, pre-sync

    const int t = threadIdx.x;
    const int lane = t & 63, wave = t >> 6;
    const int wm = wave >> 1, wn = wave & 1;
    const int quad = lane >> 4, mrow = lane & 15;
    const int row0 = by * 128, col0 = bx * 128;
    const int KSn = K >> 5;

    floatx4 acc[4][4];
#pragma unroll
    for (int i = 0; i < 4; ++i)
#pragma unroll
        for (int j = 0; j < 4; ++j)
#pragma unroll
            for (int r = 0; r < 4; ++r) acc[i][j][r] = 0.f;

    for (int kk = 0; kk < KSn; ++kk) {
        const size_t ab = ((size_t)(by * KSn + kk) * 512) * 8;
        const size_t bb = ((size_t)(bx * KSn + kk) * 512) * 8;
        uint4 ra0 = *(const uint4*)(Ap  + ab + (size_t)t * 8);
        uint4 ra1 = *(const uint4*)(Ap  + ab + (size_t)(t + 256) * 8);
        uint4 rb0 = *(const uint4*)(Btp + bb + (size_t)t * 8);
        uint4 rb1 = *(const uint4*)(Btp + bb + (size_t)(t + 256) * 8);
        __syncthreads();
        *(uint4*)&As[t * 8]         = ra0;
        *(uint4*)&As[(t + 256) * 8] = ra1;
        *(uint4*)&Bs[t * 8]         = rb0;
        *(uint4*)&Bs[(t + 256) * 8] = rb1;
        __syncthreads();

        short8 af[4], bfr[4];
#pragma unroll
        for (int i = 0; i < 4; ++i)
            af[i] = *(const short8*)&As[(wm * 256 + i * 64 + lane) * 8];
#pragma unroll
        for (int j = 0; j < 4; ++j)
            bfr[j] = *(const short8*)&Bs[(wn * 256 + j * 64 + lane) * 8];
#pragma unroll
        for (int i = 0; i < 4; ++i)
#pragma unroll
            for (int j = 0; j < 4; ++j)
                acc[i][j] = __builtin_amdgcn_mfma_f32_16x16x32_bf16(af[i], bfr[j], acc[i][j], 0, 0, 0);
    }

    // ---- fused epilogue ----
    const int head = (col0 + wn * 64) >> 6;
    float attS[4], attD[4];
#pragma unroll
    for (int j = 0; j < 4; ++j) {
        attS[j] = atts[head * 64 + j * 16 + mrow];
        attD[j] = attd[head * 64 + j * 16 + mrow];
    }

#pragma unroll
    for (int i = 0; i < 4; ++i) {
#pragma unroll
        for (int r = 0; r < 4; ++r) {
            int row = row0 + wm * 64 + i * 16 + quad * 4 + r;
            float ps = acc[i][0][r] * attS[0] + acc[i][1][r] * attS[1]
                     + acc[i][2][r] * attS[2] + acc[i][3][r] * attS[3];
            float pd = acc[i][0][r] * attD[0] + acc[i][1][r] * attD[1]
                     + acc[i][2][r] * attD[2] + acc[i][3][r] * attD[3];
#pragma unroll
            for (int o = 1; o < 16; o <<= 1) {
                ps += __shfl_xor(ps, o);
                pd += __shfl_xor(pd, o);
            }
            if (row < M) {
                if (mrow == 0) {
                    aS[(size_t)head * M + row] = ps;   // head-major
                    aD[(size_t)head * M + row] = pd;
                }
#pragma unroll
                for (int j = 0; j < 4; ++j)
                    hN[(size_t)row * N + col0 + wn * 64 + j * 16 + mrow] = f2bf(acc[i][j][r]);
            }
        }
    }
}

// ---------------------------------------------------------------------------
// GAT aggregation + FUSED BN stage-1 partials (R9/R10-proven: 43us L1).
//  (1) LDS pair stores (BYTE OFFSET = sn*F*2, p) -- no per-lane 64-bit muls.
//  (2) uint4 gathers, 2 edges per 16-lane group: lane q&7 owns 8 channels
//      (16B), q>>3 picks edge parity -> 8 edges/iter, 4 independent loads.
//  (3) epilogue: shfl_xor(.,8) cross-reduce; BN quad cq = (q&7)*2 + (q>>3).
// 32-edge chunks, first chunk peeled, head->XCD pinning (blockIdx.x % 8).
// ---------------------------------------------------------------------------
template <int HH>
__global__ __launch_bounds__(256) void gat_agg_head32(
        const unsigned short* __restrict__ hN,
        const float* __restrict__ aS, const float* __restrict__ aD,
        const int* __restrict__ rowp, const int* __restrict__ colx,
        const float* __restrict__ bias, float* __restrict__ out,
        float* __restrict__ part, int Nn) {
    constexpr int F = HH * 64;
    constexpr unsigned F2 = F * 2;            // hN row stride in bytes
    constexpr int G = 8 / HH;                 // XCDs sharing one head
    __shared__ uint2 pair[4][4][33];          // [wave][grp][edge] (byteoff, p)
    __shared__ float red[4][16][9];           // [wave][q][8 vals + pad]
    const int L = blockIdx.x;
    const int x8 = L & 7;
    const int hd = x8 / G;                    // head pinned to XCD group
    const int nodeblk = (L >> 3) * G + (x8 & (G - 1));
    const int wave = threadIdx.x >> 6, lane = threadIdx.x & 63;
    const int grp = lane >> 4;                // 4 node-tasks per wave
    const int q   = lane & 15;
    const int eo  = q >> 3;                   // edge-parity slot (0/1)
    const int lo  = (q & 7) * 16;             // lane's 8-channel byte offset
    const int n = nodeblk * 16 + wave * 4 + grp;
    const bool valid = (n < Nn);

    const char* hb = (const char*)hN + hd * 128;   // head slice base (bytes)

    float a0 = 0.f, a1 = 0.f, a2 = 0.f, a3 = 0.f;
    float a4 = 0.f, a5 = 0.f, a6 = 0.f, a7 = 0.f;
    float4 o4 = make_float4(0.f, 0.f, 0.f, 0.f);

    if (valid) {
        const float* aSh = aS + (size_t)hd * Nn;
        const float adv = aD[(size_t)hd * Nn + n];
        const int b0 = rowp[n], b1 = rowp[n + 1];

        float m, s;

        auto gather = [&](int cnt) {
            for (int j = 0; j < cnt; j += 8) {
                uint2 x0 = pair[wave][grp][j + eo + 0];
                uint2 x1 = pair[wave][grp][j + eo + 2];
                uint2 x2 = pair[wave][grp][j + eo + 4];
                uint2 x3 = pair[wave][grp][j + eo + 6];
                uint4 v0 = *(const uint4*)(hb + x0.x + lo);
                uint4 v1 = *(const uint4*)(hb + x1.x + lo);
                uint4 v2 = *(const uint4*)(hb + x2.x + lo);
                uint4 v3 = *(const uint4*)(hb + x3.x + lo);
                float p0 = __uint_as_float(x0.y), p1 = __uint_as_float(x1.y);
                float p2 = __uint_as_float(x2.y), p3 = __uint_as_float(x3.y);
                a0 += p0 * bflo(v0.x) + p1 * bflo(v1.x) + p2 * bflo(v2.x) + p3 * bflo(v3.x);
                a1 += p0 * bfhi(v0.x) + p1 * bfhi(v1.x) + p2 * bfhi(v2.x) + p3 * bfhi(v3.x);
                a2 += p0 * bflo(v0.y) + p1 * bflo(v1.y) + p2 * bflo(v2.y) + p3 * bflo(v3.y);
                a3 += p0 * bfhi(v0.y) + p1 * bfhi(v1.y) + p2 * bfhi(v2.y) + p3 * bfhi(v3.y);
                a4 += p0 * bflo(v0.z) + p1 * bflo(v1.z) + p2 * bflo(v2.z) + p3 * bflo(v3.z);
                a5 += p0 * bfhi(v0.z) + p1 * bfhi(v1.z) + p2 * bfhi(v2.z) + p3 * bfhi(v3.z);
                a6 += p0 * bflo(v0.w) + p1 * bflo(v1.w) + p2 * bflo(v2.w) + p3 * bflo(v3.w);
                a7 += p0 * bfhi(v0.w) + p1 * bfhi(v1.w) + p2 * bfhi(v2.w) + p3 * bfhi(v3.w);
            }
        };

        // ---- chunk 0 (peeled: no rescale; every node has >=1 edge) ----
        {
            const int cnt = min(32, b1 - b0);
            int sn0 = 0, sn1 = 0;
            if (q < cnt)      sn0 = colx[b0 + q];
            if (q + 16 < cnt) sn1 = colx[b0 + q + 16];
            float t0 = aSh[sn0] + adv;               // row 0 safe for pad lanes
            float t1 = aSh[sn1] + adv;
            float e0 = (q < cnt)      ? ((t0 > 0.f) ? t0 : 0.2f * t0) : -1e30f;
            float e1 = (q + 16 < cnt) ? ((t1 > 0.f) ? t1 : 0.2f * t1) : -1e30f;
            float mc = fmaxf(e0, e1);
#pragma unroll
            for (int o = 8; o > 0; o >>= 1) mc = fmaxf(mc, __shfl_xor(mc, o));
            m = mc;
            float p0 = __expf(e0 - m);               // pad lanes: exp(-1e30-m) = 0
            float p1 = __expf(e1 - m);
            float ps = p0 + p1;
#pragma unroll
            for (int o = 8; o > 0; o >>= 1) ps += __shfl_xor(ps, o);
            s = ps;
            pair[wave][grp][q]      = make_uint2((unsigned)sn0 * F2, __float_as_uint(p0));
            pair[wave][grp][q + 16] = make_uint2((unsigned)sn1 * F2, __float_as_uint(p1));
            __threadfence_block();
            gather(cnt);
        }

        // ---- chunks 1.. (deg > 32 only; rare) ----
        for (int c0 = b0 + 32; c0 < b1; c0 += 32) {
            __threadfence_block();                   // prior gather done before overwrite
            const int cnt = min(32, b1 - c0);
            int sn0 = 0, sn1 = 0;
            if (q < cnt)      sn0 = colx[c0 + q];
            if (q + 16 < cnt) sn1 = colx[c0 + q + 16];
            float t0 = aSh[sn0] + adv;
            float t1 = aSh[sn1] + adv;
            float e0 = (q < cnt)      ? ((t0 > 0.f) ? t0 : 0.2f * t0) : -1e30f;
            float e1 = (q + 16 < cnt) ? ((t1 > 0.f) ? t1 : 0.2f * t1) : -1e30f;
            float mc = fmaxf(e0, e1);
#pragma unroll
            for (int o = 8; o > 0; o >>= 1) mc = fmaxf(mc, __shfl_xor(mc, o));
            float nm = fmaxf(m, mc);
            float sc = __expf(m - nm);
            float p0 = __expf(e0 - nm);
            float p1 = __expf(e1 - nm);
            float ps = p0 + p1;
#pragma unroll
            for (int o = 8; o > 0; o >>= 1) ps += __shfl_xor(ps, o);
            s = s * sc + ps;
            a0 *= sc; a1 *= sc; a2 *= sc; a3 *= sc;
            a4 *= sc; a5 *= sc; a6 *= sc; a7 *= sc;
            m = nm;
            pair[wave][grp][q]      = make_uint2((unsigned)sn0 * F2, __float_as_uint(p0));
            pair[wave][grp][q + 16] = make_uint2((unsigned)sn1 * F2, __float_as_uint(p1));
            __threadfence_block();
            gather(cnt);
        }

        // cross-reduce the even/odd edge partials (lanes q and q+8 share chans)
        a0 += __shfl_xor(a0, 8); a1 += __shfl_xor(a1, 8);
        a2 += __shfl_xor(a2, 8); a3 += __shfl_xor(a3, 8);
        a4 += __shfl_xor(a4, 8); a5 += __shfl_xor(a5, 8);
        a6 += __shfl_xor(a6, 8); a7 += __shfl_xor(a7, 8);

        const float inv = 1.f / s;
        float r0 = eo ? a4 : a0;
        float r1 = eo ? a5 : a1;
        float r2 = eo ? a6 : a2;
        float r3 = eo ? a7 : a3;
        const int cb = hd * 64 + (q & 7) * 8 + eo * 4;
        o4.x = r0 * inv + bias[cb + 0];
        o4.y = r1 * inv + bias[cb + 1];
        o4.z = r2 * inv + bias[cb + 2];
        o4.w = r3 * inv + bias[cb + 3];
        *(float4*)(out + (size_t)n * F + cb) = o4;
    }

    // ---- fused BN stage-1: per-block sum/sumsq of 64 channels over 16 nodes
    float s0 = o4.x, s1 = o4.y, s2 = o4.z, s3 = o4.w;
    float q0 = s0 * s0, q1 = s1 * s1, q2 = s2 * s2, q3 = s3 * s3;
#pragma unroll
    for (int o = 16; o < 64; o <<= 1) {        // sum over the 4 nodes in wave
        s0 += __shfl_xor(s0, o); s1 += __shfl_xor(s1, o);
        s2 += __shfl_xor(s2, o); s3 += __shfl_xor(s3, o);
        q0 += __shfl_xor(q0, o); q1 += __shfl_xor(q1, o);
        q2 += __shfl_xor(q2, o); q3 += __shfl_xor(q3, o);
    }
    if (grp == 0) {
        red[wave][q][0] = s0; red[wave][q][1] = s1;
        red[wave][q][2] = s2; red[wave][q][3] = s3;
        red[wave][q][4] = q0; red[wave][q][5] = q1;
        red[wave][q][6] = q2; red[wave][q][7] = q3;
    }
    __syncthreads();
    if (wave == 0 && lane < 16) {
        float a[8];
#pragma unroll
        for (int k = 0; k < 8; ++k)
            a[k] = red[0][q][k] + red[1][q][k] + red[2][q][k] + red[3][q][k];
        // lane q's 4 written channels start at (q&7)*8 + eo*4 -> quad index:
        const int cq = (q & 7) * 2 + eo;
        float* pb = part + (size_t)L * 128;
#pragma unroll
        for (int k = 0; k < 4; ++k) {
            pb[cq * 4 + k]      = a[k];
            pb[64 + cq * 4 + k] = a[4 + k];
        }
    }
}

// ---------------------------------------------------------------------------
// Layer-4 GEMM with FUSED BN+ELU A-staging (R8-proven): reads layer-3 agg
// output bufO fp32, applies bns (K=128) + ELU during As staging (fp32 in
// LDS -- no quantization). N=16. Writes bf16 hN and fused att dots (H=1).
// ---------------------------------------------------------------------------
__global__ __launch_bounds__(256) void gemm_l4_fused(const float* __restrict__ A,
                                                     const float* __restrict__ B,
                                                     unsigned short* __restrict__ C,
                                                     float* __restrict__ aS, float* __restrict__ aD,
                                                     const float* __restrict__ atts,
                                                     const float* __restrict__ attd,
                                                     const float* __restrict__ ssg,
                                                     int M, int N, int K, int Mreal) {
    __shared__ float As[16][65];
    __shared__ float Bs[16][64];
    const int tid = threadIdx.x;
    const int tx = tid & 15, ty = tid >> 4;
    const int row0 = blockIdx.y * 64, col0 = blockIdx.x * 64;
    const int rA = tid >> 2, kq = (tid & 3) << 2;
    const int rB = tid >> 4, cq = (tid & 15) << 2;
    float acc[4][4] = {};

    for (int k0 = 0; k0 < K; k0 += 16) {
        const int arow = row0 + rA;
        float a0v = 0.f, a1v = 0.f, a2v = 0.f, a3v = 0.f;
        if (arow < Mreal) {
            float4 fa = *(const float4*)(A + (size_t)arow * K + k0 + kq);
            const int c = k0 + kq;
            a0v = fa.x * ssg[c + 0] + ssg[K + c + 0];
            a1v = fa.y * ssg[c + 1] + ssg[K + c + 1];
            a2v = fa.z * ssg[c + 2] + ssg[K + c + 2];
            a3v = fa.w * ssg[c + 3] + ssg[K + c + 3];
            a0v = (a0v > 0.f) ? a0v : (__expf(a0v) - 1.f);
            a1v = (a1v > 0.f) ? a1v : (__expf(a1v) - 1.f);
            a2v = (a2v > 0.f) ? a2v : (__expf(a2v) - 1.f);
            a3v = (a3v > 0.f) ? a3v : (__expf(a3v) - 1.f);
        }
        float4 fb = make_float4(0.f, 0.f, 0.f, 0.f);
        int bcol = col0 + cq;
        if (bcol < N) fb = *(const float4*)(B + (size_t)(k0 + rB) * N + bcol);
        As[kq + 0][rA] = a0v; As[kq + 1][rA] = a1v;
        As[kq + 2][rA] = a2v; As[kq + 3][rA] = a3v;
        *(float4*)&Bs[rB][cq] = fb;
        __syncthreads();
#pragma unroll
        for (int k = 0; k < 16; ++k) {
            float a0 = As[k][ty * 4 + 0];
            float a1 = As[k][ty * 4 + 1];
            float a2 = As[k][ty * 4 + 2];
            float a3 = As[k][ty * 4 + 3];
            float4 b = *(float4*)&Bs[k][tx * 4];
            acc[0][0] += a0 * b.x; acc[0][1] += a0 * b.y; acc[0][2] += a0 * b.z; acc[0][3] += a0 * b.w;
            acc[1][0] += a1 * b.x; acc[1][1] += a1 * b.y; acc[1][2] += a1 * b.z; acc[1][3] += a1 * b.w;
            acc[2][0] += a2 * b.x; acc[2][1] += a2 * b.y; acc[2][2] += a2 * b.z; acc[2][3] += a2 * b.w;
            acc[3][0] += a3 * b.x; acc[3][1] += a3 * b.y; acc[3][2] += a3 * b.z; acc[3][3] += a3 * b.w;
        }
        __syncthreads();
    }
    float as_part[4], ad_part[4];
#pragma unroll
    for (int i = 0; i < 4; ++i) { as_part[i] = 0.f; ad_part[i] = 0.f; }
    if (tx < 4) {
#pragma unroll
        for (int i = 0; i < 4; ++i) {
#pragma unroll
            for (int jj = 0; jj < 4; ++jj) {
                int c = tx * 4 + jj;
                as_part[i] += acc[i][jj] * atts[c];
                ad_part[i] += acc[i][jj] * attd[c];
            }
        }
    }
#pragma unroll
    for (int i = 0; i < 4; ++i) {
        float ps = as_part[i], pd = ad_part[i];
        ps += __shfl_xor(ps, 1); ps += __shfl_xor(ps, 2);
        pd += __shfl_xor(pd, 1); pd += __shfl_xor(pd, 2);
        int r = row0 + ty * 4 + i;
        if (r < M) {
            if (tx == 0) { aS[r] = ps; aD[r] = pd; }
#pragma unroll
            for (int jj = 0; jj < 4; ++jj) {
                int c = col0 + tx * 4 + jj;
                if (c < N) C[(size_t)r * N + c] = f2bf(acc[i][jj]);
            }
        }
    }
}

// ---------------------------------------------------------------------------
// Layer-4 aggregation (H=1, C=16) with FUSED log_softmax. One wave per node.
// ---------------------------------------------------------------------------
template <int C>
__global__ void gat_agg_l4_ls(const unsigned short* __restrict__ ht,
                              const float* __restrict__ as, const float* __restrict__ aD,
                              const int* __restrict__ rowp, const int* __restrict__ colx,
                              const float* __restrict__ bias, float* __restrict__ out, int Nn) {
    int n = blockIdx.x * 4 + (threadIdx.x >> 6);
    int lane = threadIdx.x & 63;
    if (n >= Nn) return;
    float adv = aD[n];
    int b0 = rowp[n], b1 = rowp[n + 1];

    float m = -1e30f, s = 0.f, acc = 0.f;
    for (int c0 = b0; c0 < b1; c0 += 64) {
        int cnt = b1 - c0; if (cnt > 64) cnt = 64;
        int sn = 0; float e = -1e30f;
        if (lane < cnt) {
            sn = colx[c0 + lane];
            float tt = as[sn] + adv;
            e = (tt > 0.f) ? tt : 0.2f * tt;
        }
        float mc = e;
#pragma unroll
        for (int o = 32; o > 0; o >>= 1) mc = fmaxf(mc, __shfl_xor(mc, o));
        float nm = fmaxf(m, mc);
        float sc = __expf(m - nm);
        acc *= sc; s *= sc;
        float p = (lane < cnt) ? __expf(e - nm) : 0.f;
        float ps = p;
#pragma unroll
        for (int o = 32; o > 0; o >>= 1) ps += __shfl_xor(ps, o);
        s += ps; m = nm;

        int j = 0;
        for (; j + 4 <= cnt; j += 4) {
            int s0 = __shfl(sn, j),     s1 = __shfl(sn, j + 1);
            int s2 = __shfl(sn, j + 2), s3 = __shfl(sn, j + 3);
            float p0 = __shfl(p, j),     p1 = __shfl(p, j + 1);
            float p2 = __shfl(p, j + 2), p3 = __shfl(p, j + 3);
            float h0 = 0.f, h1 = 0.f, h2 = 0.f, h3 = 0.f;
            if (lane < C) {
                h0 = bf2f(ht[(size_t)s0 * C + lane]);
                h1 = bf2f(ht[(size_t)s1 * C + lane]);
                h2 = bf2f(ht[(size_t)s2 * C + lane]);
                h3 = bf2f(ht[(size_t)s3 * C + lane]);
            }
            acc += p0 * h0 + p1 * h1 + p2 * h2 + p3 * h3;
        }
        for (; j < cnt; ++j) {
            int sj = __shfl(sn, j);
            float pj = __shfl(p, j);
            float hv = (lane < C) ? bf2f(ht[(size_t)sj * C + lane]) : 0.f;
            acc += pj * hv;
        }
    }
    float v = (lane < C) ? (acc / s + bias[lane]) : -1e30f;
    float mx = v;
#pragma unroll
    for (int o = 8; o > 0; o >>= 1) mx = fmaxf(mx, __shfl_xor(mx, o));
    float ex = (lane < C) ? __expf(v - mx) : 0.f;
#pragma unroll
    for (int o = 8; o > 0; o >>= 1) ex += __shfl_xor(ex, o);
    float l = __logf(ex) + mx;
    if (lane < C) out[(size_t)n * C + lane] = v - l;
}

// ---------------------------------------------------------------------------
// BN final reduce over the agg kernel's per-block partials (R7-proven: 1024
// threads, 32 partial-rows, 4 independent accumulators -> short dep chain).
// Fixed iteration order -> deterministic.
// ---------------------------------------------------------------------------
template <int F>
__global__ __launch_bounds__(1024) void bn_reduce_par(const float* __restrict__ part,
                                                      const float* __restrict__ gamma,
                                                      const float* __restrict__ beta,
                                                      float* __restrict__ ss,
                                                      float invN, int NB8) {
    constexpr int G = 512 / F;      // XCD-groups per head (matches agg's G)
    __shared__ float sd[32][33];
    const int t = threadIdx.x;
    const int pr = t >> 5;          // partial-row 0..31
    const int tg = t & 31;          // 0-15: sum of col c0+tg; 16-31: sumsq
    const int c0 = blockIdx.x * 16;
    const int c  = c0 + (tg & 15);
    const int hd = c >> 6;
    const int off = (c & 63) + ((tg < 16) ? 0 : 64);
    float a0 = 0.f, a1 = 0.f, a2 = 0.f, a3 = 0.f;
    for (int g = 0; g < G; ++g) {
        const float* pb = part + (size_t)(hd * G + g) * 128 + off;
        int j = pr;
        for (; j + 96 < NB8; j += 128) {        // 4 independent loads in flight
            a0 += pb[(size_t)(j +  0) * 1024];
            a1 += pb[(size_t)(j + 32) * 1024];
            a2 += pb[(size_t)(j + 64) * 1024];
            a3 += pb[(size_t)(j + 96) * 1024];
        }
        for (; j < NB8; j += 32)
            a0 += pb[(size_t)j * 1024];
    }
    sd[pr][tg] = (a0 + a1) + (a2 + a3);
    __syncthreads();
    if (pr == 0) {
        float tot = sd[0][tg];
#pragma unroll
        for (int r = 1; r < 32; ++r) tot += sd[r][tg];   // fixed serial order
        sd[0][tg] = tot;
    }
    __syncthreads();
    if (t < 16) {
        int cc = c0 + t;
        float s = sd[0][t];
        float q = sd[0][16 + t];
        float mu = s * invN;
        float var = q * invN - mu * mu;
        float sc = gamma[cc] * rsqrtf(var + 1e-5f);
        ss[cc] = sc;
        ss[F + cc] = beta[cc] - mu * sc;
    }
}

// ---------------------------------------------------------------------------
// Launcher. 18 dispatches: CSR(4) + prep_all + [gemm, agg, reduce] x1 +
// [bn_apply_perm, gemm, agg, reduce] x2 + gemm_l4 + agg_l4.
// All MFMA-GEMM operands pre-permuted to tile-fragment order.
// ---------------------------------------------------------------------------
extern "C" void kernel_launch(void* const* d_in, const int* in_sizes, int n_in,
                              void* d_out, int out_size, void* d_ws, size_t ws_size,
                              hipStream_t stream) {
    const float* x   = (const float*)d_in[0];
    const int*   ei  = (const int*)d_in[1];
    const float* W1  = (const float*)d_in[2];
    const float* as1 = (const float*)d_in[3];
    const float* ad1 = (const float*)d_in[4];
    const float* b1  = (const float*)d_in[5];
    const float* ga1 = (const float*)d_in[6];
    const float* be1 = (const float*)d_in[7];
    const float* W2  = (const float*)d_in[8];
    const float* as2 = (const float*)d_in[9];
    const float* ad2 = (const float*)d_in[10];
    const float* b2  = (const float*)d_in[11];
    const float* ga2 = (const float*)d_in[12];
    const float* be2 = (const float*)d_in[13];
    const float* W3  = (const float*)d_in[14];
    const float* as3 = (const float*)d_in[15];
    const float* ad3 = (const float*)d_in[16];
    const float* b3  = (const float*)d_in[17];
    const float* ga3 = (const float*)d_in[18];
    const float* be3 = (const float*)d_in[19];
    const float* W4  = (const float*)d_in[20];
    const float* as4 = (const float*)d_in[21];
    const float* ad4 = (const float*)d_in[22];
    const float* b4  = (const float*)d_in[23];
    float* outp = (float*)d_out;

    uint8_t* base = (uint8_t*)d_ws;
    size_t off = 0;
    auto alloc = [&](size_t nbytes) -> void* {
        off = (off + 255) & ~(size_t)255;
        void* p = base + off;
        off += nbytes;
        return p;
    };
    float* bufO = (float*)alloc((size_t)NN * 512 * 4);                       // agg out (fp32)
    unsigned short* Ap   = (unsigned short*)alloc((size_t)NA_CHUNKS * 8 * 2);// permuted bf16 A
    unsigned short* hN   = (unsigned short*)alloc((size_t)NN * 512 * 2);     // bf16 node-major h
    unsigned short* Wt1  = (unsigned short*)alloc((size_t)W1C * 8 * 2);
    unsigned short* Wt2  = (unsigned short*)alloc((size_t)W2C * 8 * 2);
    unsigned short* Wt3  = (unsigned short*)alloc((size_t)W3C * 8 * 2);
    float* aSn  = (float*)alloc((size_t)NN * 8 * 4);
    float* aDn  = (float*)alloc((size_t)NN * 8 * 4);
    int*   cnt  = (int*)alloc((size_t)NN * 4);
    int*   rowp = (int*)alloc((size_t)(NN + 1) * 4);
    int*   wptr = (int*)alloc((size_t)NN * 4);
    int*   colx = (int*)alloc((size_t)ET * 4);
    float* bnp  = (float*)alloc((size_t)10048 * 128 * 4);    // agg-block BN partials
    float* bns  = (float*)alloc((size_t)1024 * 4);           // scale/shift

    const int* srcRow = ei;
    const int* dstRow = ei + EE;

    // ---- CSR build ----
    zero_i32<<<(NN + 255) / 256, 256, 0, stream>>>(cnt, NN);
    count_edges<<<(ET + 255) / 256, 256, 0, stream>>>(dstRow, cnt);
    scan_fast<<<1, 1024, 0, stream>>>(cnt, rowp, wptr, NN);
    fill_edges<<<(ET + 255) / 256, 256, 0, stream>>>(srcRow, dstRow, wptr, colx);

    // ---- permuted A(x) + permuted weights, one dispatch ----
    prep_all<<<NA_BLOCKS + NW_BLOCKS, 256, 0, stream>>>(x, Ap, W1, Wt1, W2, Wt2, W3, Wt3);

    const int NBLK = (NN + 15) / 16;   // 16-node task blocks (=1250)
    const int GY8 = 160;               // 157 row-panels padded to mult of 8

    // ---- Layer 1: Fin=512, H=8, C=64 (F=512) ----
    {
        gemm_bf16_fused<<<4 * GY8, 256, 0, stream>>>(Ap, Wt1, hN, aSn, aDn, as1, ad1,
                                                     NN, 512, 512, 2, 157);
        gat_agg_head32<8><<<NBLK * 8, 256, 0, stream>>>(hN, aSn, aDn, rowp, colx, b1, bufO, bnp, NN);
        bn_reduce_par<512><<<512 / 16, 1024, 0, stream>>>(bnp, ga1, be1, bns, 1.0f / NN, NBLK);
    }
    // ---- Layer 2: Fin=512, H=4, C=64 (F=256) ----
    {
        bn_apply_perm<512><<<(157 * 16 * 512) / 256, 256, 0, stream>>>(bufO, bns, Ap, NN);
        gemm_bf16_fused<<<2 * GY8, 256, 0, stream>>>(Ap, Wt2, hN, aSn, aDn, as2, ad2,
                                                     NN, 256, 512, 1, 157);
        const int nb8 = (NBLK + 1) / 2;
        gat_agg_head32<4><<<nb8 * 8, 256, 0, stream>>>(hN, aSn, aDn, rowp, colx, b2, bufO, bnp, NN);
        bn_reduce_par<256><<<256 / 16, 1024, 0, stream>>>(bnp, ga2, be2, bns, 1.0f / NN, nb8);
    }
    // ---- Layer 3: Fin=256, H=2, C=64 (F=128) ----
    {
        bn_apply_perm<256><<<(157 * 8 * 512) / 256, 256, 0, stream>>>(bufO, bns, Ap, NN);
        gemm_bf16_fused<<<1 * GY8, 256, 0, stream>>>(Ap, Wt3, hN, aSn, aDn, as3, ad3,
                                                     NN, 128, 256, 0, 157);
        const int nb8 = (NBLK + 3) / 4;
        gat_agg_head32<2><<<nb8 * 8, 256, 0, stream>>>(hN, aSn, aDn, rowp, colx, b3, bufO, bnp, NN);
        bn_reduce_par<128><<<128 / 16, 1024, 0, stream>>>(bnp, ga3, be3, bns, 1.0f / NN, nb8);
    }
    // ---- Layer 4: Fin=128, H=1, C=16; BN+ELU fused into A-staging (fp32) ----
    {
        dim3 g(1, (NN + 63) / 64);
        gemm_l4_fused<<<g, 256, 0, stream>>>(bufO, W4, hN, aSn, aDn, as4, ad4,
                                             bns, NN, 16, 128, NN);
        gat_agg_l4_ls<16><<<(NN + 3) / 4, 256, 0, stream>>>(hN, aSn, aDn, rowp, colx, b4, outp, NN);
    }
}